// Round 19
// baseline (35.718 us; speedup 1.0000x reference)
//
#include <hip/hip_runtime.h>
#include <stdint.h>

#define BINS    64
#define SBINS   256               // sub-bins: 4 per bin (h = 1/4 bin)
#define CSTR    66                // dwords per u8-count column (64 + 2 pad)
#define THREADS 128
#define CHUNKS  32                // blocks per channel-image
#define NPIX    (512*512)
#define PPB     (NPIX / CHUNKS)   // 8192 px per block -> 64 px/thread (u8 max 64 < 255)
#define ITERS   (PPB / 4 / THREADS)   // 16
#define NCH     12
#define NIMG    (2 * NCH)         // 24
#define ARRIV   (CHUNKS * 2)      // 64 blocks feed each channel pair
#define PPW     128               // packed u32 (u16 sub-bin pair) per chunk store

// Agent-scope (device-coherent) accesses for all cross-block data.
__device__ __forceinline__ uint32_t cload(const uint32_t* p) {
    return __hip_atomic_load(p, __ATOMIC_RELAXED, __HIP_MEMORY_SCOPE_AGENT);
}
__device__ __forceinline__ void cstore(uint32_t* p, uint32_t v) {
    __hip_atomic_store(p, v, __ATOMIC_RELAXED, __HIP_MEMORY_SCOPE_AGENT);
}

__global__ __launch_bounds__(THREADS) void fused_kernel(
    const float* __restrict__ pred, const float* __restrict__ target,
    uint32_t* __restrict__ part /* [NIMG][CHUNKS][PPW] u16-pairs */,
    uint32_t* __restrict__ tickets /* [NCH] per-channel + [1] global; ZEROED */,
    uint32_t* __restrict__ partial /* [NCH] float bits */,
    float* __restrict__ out)
{
    __shared__ uint32_t lh[THREADS * CSTR];   // 33792 B
    __shared__ uint32_t red[2 * THREADS];
    __shared__ uint32_t lastflag;
    const int tid = threadIdx.x;

    uint32_t* col = &lh[tid * CSTR];
    uint2* colv = (uint2*)col;
    #pragma unroll
    for (int i = 0; i < CSTR / 2; ++i) colv[i] = make_uint2(0u, 0u);
    __syncthreads();

    const int chunk = blockIdx.x;
    const int ch    = blockIdx.y;
    const int z     = blockIdx.z;
    const float* src = (z == 0 ? pred : target)
                     + (size_t)ch * NPIX + (size_t)chunk * PPB;
    const float4* src4 = (const float4*)src;

    // deposit: prefetch depth 2, u8-lane counts in private columns
    float4 v0 = src4[tid];
    float4 v1 = src4[THREADS + tid];
    #pragma unroll
    for (int k = 0; k < ITERS; ++k) {
        float4 v2 = (k + 2 < ITERS) ? src4[(size_t)(k + 2) * THREADS + tid]
                                    : make_float4(0.f, 0.f, 0.f, 0.f);
        float xv[4] = {v0.x, v0.y, v0.z, v0.w};
        #pragma unroll
        for (int e = 0; e < 4; ++e) {
            uint32_t kq = (uint32_t)(int)(xv[e] * 256.0f);   // sub-bin 0..255
            col[kq >> 2] += 1u << ((kq & 3u) << 3);
        }
        v0 = v1; v1 = v2;
    }
    __syncthreads();

    // SIMD fold in packed u16 lanes
    const int d = tid & 63;
    const int g = tid >> 6;
    uint32_t lo = 0u, hi = 0u;
    #pragma unroll 8
    for (int c = 0; c < 64; ++c) {
        uint32_t x = lh[(g * 64 + c) * CSTR + d];
        lo += x & 0x00FF00FFu;
        hi += (x >> 8) & 0x00FF00FFu;
    }
    red[tid] = lo;
    red[THREADS + tid] = hi;
    __syncthreads();

    if (tid < 64) {
        uint32_t tlo = red[tid] + red[tid + 64];                      // {4d, 4d+2}
        uint32_t thi = red[THREADS + tid] + red[THREADS + tid + 64];  // {4d+1, 4d+3}
        uint32_t w0 = (tlo & 0xFFFFu) | ((thi & 0xFFFFu) << 16);      // 4d, 4d+1
        uint32_t w1 = (tlo >> 16) | ((thi >> 16) << 16);              // 4d+2, 4d+3
        uint32_t* pp = part + (((size_t)z * NCH + ch) * CHUNKS + chunk) * PPW + 2 * d;
        cstore(pp + 0, w0);
        cstore(pp + 1, w1);
    }
    __syncthreads();

    if (tid == 0) {
        // tickets zeroed by memset each launch -> old == ARRIV-1 is the TRUE
        // last arrival (R17/R18 bug: poison base made residue fire early).
        uint32_t old = __hip_atomic_fetch_add(&tickets[ch], 1u,
                          __ATOMIC_ACQ_REL, __HIP_MEMORY_SCOPE_AGENT);
        lastflag = (old == ARRIV - 1u) ? 1u : 0u;
    }
    __syncthreads();
    if (!lastflag) return;

    // ---- tail (the last-arriving block of each channel pair) ----
    uint32_t sP0 = 0u, sP1 = 0u, sT0 = 0u, sT1 = 0u;
    {
        const uint32_t* baseP = part + ((size_t)(0 * NCH + ch) * CHUNKS) * PPW + tid;
        const uint32_t* baseT = part + ((size_t)(1 * NCH + ch) * CHUNKS) * PPW + tid;
        #pragma unroll
        for (int i = 0; i < CHUNKS; i += 8) {
            uint32_t a0 = cload(baseP + (size_t)(i + 0) * PPW);
            uint32_t a1 = cload(baseP + (size_t)(i + 1) * PPW);
            uint32_t a2 = cload(baseP + (size_t)(i + 2) * PPW);
            uint32_t a3 = cload(baseP + (size_t)(i + 3) * PPW);
            uint32_t a4 = cload(baseP + (size_t)(i + 4) * PPW);
            uint32_t a5 = cload(baseP + (size_t)(i + 5) * PPW);
            uint32_t a6 = cload(baseP + (size_t)(i + 6) * PPW);
            uint32_t a7 = cload(baseP + (size_t)(i + 7) * PPW);
            uint32_t b0 = cload(baseT + (size_t)(i + 0) * PPW);
            uint32_t b1 = cload(baseT + (size_t)(i + 1) * PPW);
            uint32_t b2 = cload(baseT + (size_t)(i + 2) * PPW);
            uint32_t b3 = cload(baseT + (size_t)(i + 3) * PPW);
            uint32_t b4 = cload(baseT + (size_t)(i + 4) * PPW);
            uint32_t b5 = cload(baseT + (size_t)(i + 5) * PPW);
            uint32_t b6 = cload(baseT + (size_t)(i + 6) * PPW);
            uint32_t b7 = cload(baseT + (size_t)(i + 7) * PPW);
            sP0 += (a0 & 0xFFFFu) + (a1 & 0xFFFFu) + (a2 & 0xFFFFu) + (a3 & 0xFFFFu)
                 + (a4 & 0xFFFFu) + (a5 & 0xFFFFu) + (a6 & 0xFFFFu) + (a7 & 0xFFFFu);
            sP1 += (a0 >> 16) + (a1 >> 16) + (a2 >> 16) + (a3 >> 16)
                 + (a4 >> 16) + (a5 >> 16) + (a6 >> 16) + (a7 >> 16);
            sT0 += (b0 & 0xFFFFu) + (b1 & 0xFFFFu) + (b2 & 0xFFFFu) + (b3 & 0xFFFFu)
                 + (b4 & 0xFFFFu) + (b5 & 0xFFFFu) + (b6 & 0xFFFFu) + (b7 & 0xFFFFu);
            sT1 += (b0 >> 16) + (b1 >> 16) + (b2 >> 16) + (b3 >> 16)
                 + (b4 >> 16) + (b5 >> 16) + (b6 >> 16) + (b7 >> 16);
        }
    }
    __syncthreads();                        // deposit lh dead; safe to reuse
    float* cntP  = (float*)lh;              // [SBINS]
    float* cntT  = cntP + SBINS;            // [SBINS]
    float* histP = cntT + SBINS;            // [BINS]
    float* histT = histP + BINS;            // [BINS]
    cntP[2 * tid]     = (float)sP0;
    cntP[2 * tid + 1] = (float)sP1;
    cntT[2 * tid]     = (float)sT0;
    cntT[2 * tid + 1] = (float)sT1;
    __syncthreads();

    {   // conv: tid<64 -> pred bin tid ; tid>=64 -> target bin tid-64
        const int b = tid & 63;
        const float* cnt = (tid < 64) ? cntP : cntT;
        float h = 0.0f;
        #pragma unroll
        for (int u = -16; u <= 19; ++u) {
            int idx = 4 * b + u;
            if (idx >= 0 && idx < SBINS) {
                float t = (u - 1.5f) * 0.25f;
                h += __expf(-0.5f * t * t) * cnt[idx];
            }
        }
        if (tid < 64) histP[b] = h; else histT[b] = h;
    }
    __syncthreads();

    if (tid < 64) {                 // wave 0: dual CDF + |diff| sum
        float cp = histP[tid], ct = histT[tid];
        #pragma unroll
        for (int off = 1; off < 64; off <<= 1) {
            float a = __shfl_up(cp, off, 64);
            float b = __shfl_up(ct, off, 64);
            if (tid >= off) { cp += a; ct += b; }
        }
        float sp = __shfl(cp, 63, 64);
        float st = __shfl(ct, 63, 64);
        float diff = fabsf(cp / (sp + 1e-8f) - ct / (st + 1e-8f));
        #pragma unroll
        for (int off = 32; off; off >>= 1)
            diff += __shfl_xor(diff, off, 64);
        if (tid == 0) {
            cstore(&partial[ch], __float_as_uint(diff));
            uint32_t old = __hip_atomic_fetch_add(&tickets[NCH], 1u,
                              __ATOMIC_ACQ_REL, __HIP_MEMORY_SCOPE_AGENT);
            if (old == (uint32_t)(NCH - 1)) {           // true last channel
                float acc = 0.0f;
                #pragma unroll
                for (int i = 0; i < NCH; ++i)
                    acc += __uint_as_float(cload(&partial[i]));
                out[0] = acc / (float)(NCH * BINS);
            }
        }
    }
}

extern "C" void kernel_launch(void* const* d_in, const int* in_sizes, int n_in,
                              void* d_out, int out_size, void* d_ws, size_t ws_size,
                              hipStream_t stream)
{
    const float* pred   = (const float*)d_in[0];
    const float* target = (const float*)d_in[1];
    uint32_t* part    = (uint32_t*)d_ws;                       // 24*32*128 u32 = 393 KB
    uint32_t* tickets = part + (size_t)NIMG * CHUNKS * PPW;    // 13 u32
    uint32_t* partial = tickets + NCH + 1;                     // 12 u32 (float bits)

    // Zero ONLY the tickets (52 B) so "last arrival" detection is exact.
    hipMemsetAsync(tickets, 0, (NCH + 1) * sizeof(uint32_t), stream);
    fused_kernel<<<dim3(CHUNKS, NCH, 2), THREADS, 0, stream>>>(
        pred, target, part, tickets, partial, (float*)d_out);
}

// Round 20
// 16.999 us; speedup vs baseline: 2.1012x; 2.1012x over previous
//
#include <hip/hip_runtime.h>
#include <stdint.h>

#define BINS    64
#define SB      3                 // sub-bins per bin
#define SBINS   (BINS * SB)       // 192
#define NDW     (SBINS / 4)       // 48 u8-count dwords per column
#define CSTR    50                // dwords per column (48 + 2 pad) -> 25.6KB/block
#define THREADS 128
#define CHUNKS  32                // blocks per channel-image
#define NPIX    (512*512)
#define PPB     (NPIX / CHUNKS)   // 8192 px per block -> 64 px/thread (u8 max 64 < 255)
#define ITERS   (PPB / 4 / THREADS)   // 16
#define NCH     12
#define NIMG    (2 * NCH)         // 24

__global__ __launch_bounds__(THREADS) void hist_kernel(
    const float* __restrict__ pred, const float* __restrict__ target,
    uint32_t* __restrict__ part /* [NIMG][CHUNKS][SBINS] */,
    uint32_t* __restrict__ ticket)
{
    __shared__ uint32_t lh[THREADS * CSTR];   // 25600 B -> 6 blocks/CU resident
    __shared__ uint32_t red[2 * THREADS];
    const int tid = threadIdx.x;

    if (blockIdx.x == 0 && blockIdx.y == 0 && blockIdx.z == 0 && tid == 0)
        *ticket = 0u;                         // re-arm conv ticket each launch

    uint32_t* col = &lh[tid * CSTR];
    uint2* colv = (uint2*)col;
    #pragma unroll
    for (int i = 0; i < CSTR / 2; ++i) colv[i] = make_uint2(0u, 0u);
    __syncthreads();

    const int chunk = blockIdx.x;
    const int ch    = blockIdx.y;
    const int z     = blockIdx.z;
    const float* src = (z == 0 ? pred : target)
                     + (size_t)ch * NPIX + (size_t)chunk * PPB;
    const float4* src4 = (const float4*)src;

    // prefetch depth 2
    float4 v0 = src4[tid];
    float4 v1 = src4[THREADS + tid];
    #pragma unroll
    for (int k = 0; k < ITERS; ++k) {
        float4 v2 = (k + 2 < ITERS) ? src4[(size_t)(k + 2) * THREADS + tid]
                                    : make_float4(0.f, 0.f, 0.f, 0.f);
        float xv[4] = {v0.x, v0.y, v0.z, v0.w};
        #pragma unroll
        for (int e = 0; e < 4; ++e) {
            uint32_t kq = (uint32_t)(int)(xv[e] * (float)SBINS);  // sub-bin 0..191
            col[kq >> 2] += 1u << ((kq & 3u) << 3);               // u8-lane count
        }
        v0 = v1; v1 = v2;
    }
    __syncthreads();

    // SIMD fold in packed u16 lanes: thread t sums dword d = t&63 (d<48)
    // over 64 columns (half g = t>>6). lo: sub-bins {4d,4d+2}; hi: {4d+1,4d+3}.
    const int d = tid & 63;
    const int g = tid >> 6;
    uint32_t lo = 0u, hi = 0u;
    if (d < NDW) {
        #pragma unroll 8
        for (int c = 0; c < 64; ++c) {
            uint32_t x = lh[(g * 64 + c) * CSTR + d];
            lo += x & 0x00FF00FFu;
            hi += (x >> 8) & 0x00FF00FFu;
        }
    }
    red[tid] = lo;
    red[THREADS + tid] = hi;
    __syncthreads();

    if (tid < NDW) {
        uint32_t tlo = red[tid] + red[tid + 64];
        uint32_t thi = red[THREADS + tid] + red[THREADS + tid + 64];
        uint4 o;
        o.x = tlo & 0xFFFFu;        // sub-bin 4d
        o.y = thi & 0xFFFFu;        // sub-bin 4d+1
        o.z = tlo >> 16;            // sub-bin 4d+2
        o.w = thi >> 16;            // sub-bin 4d+3
        uint4* pp = (uint4*)(part + (((size_t)z * NCH + ch) * CHUNKS + chunk) * SBINS);
        pp[tid] = o;                // coalesced 16B/lane store
    }
}

// 12 blocks (one per channel pair): fold partials for pred+target, 27-tap
// Gaussian conv, dual CDF, |dCDF| partial; last block (ticket) sums -> out.
__global__ __launch_bounds__(256) void conv_fin_kernel(
    const uint32_t* __restrict__ part, float* __restrict__ partial,
    uint32_t* __restrict__ ticket, float* __restrict__ out)
{
    __shared__ float cntP[SBINS], cntT[SBINS];
    __shared__ float histP[BINS], histT[BINS];
    const int ci = blockIdx.x;          // channel 0..11
    const int s  = threadIdx.x;         // 0..255

    if (s < SBINS) {
        uint32_t tp = 0u, tt = 0u;
        #pragma unroll 8
        for (int i = 0; i < CHUNKS; ++i) {
            tp += part[((size_t)ci * CHUNKS + i) * SBINS + s];
            tt += part[((size_t)(NCH + ci) * CHUNKS + i) * SBINS + s];
        }
        cntP[s] = (float)tp;
        cntT[s] = (float)tt;
    }
    __syncthreads();

    if (s < 2 * BINS) {
        const int b = s & 63;
        const float* cnt = (s < BINS) ? cntP : cntT;
        // hist_b = sum_u K(u) * cnt[3b+u], K(u) = exp(-(((u-1)/3)^2)/2)
        float h = 0.0f;
        #pragma unroll
        for (int u = -12; u <= 14; ++u) {
            int idx = SB * b + u;
            if (idx >= 0 && idx < SBINS) {
                float t = (float)(u - 1) * (1.0f / (float)SB);
                h += __expf(-0.5f * t * t) * cnt[idx];
            }
        }
        if (s < BINS) histP[b] = h; else histT[b] = h;
    }
    __syncthreads();

    if (s < 64) {                       // wave 0: dual CDF + |diff| sum
        float cp = histP[s], ct = histT[s];
        #pragma unroll
        for (int off = 1; off < 64; off <<= 1) {
            float a = __shfl_up(cp, off, 64);
            float b = __shfl_up(ct, off, 64);
            if (s >= off) { cp += a; ct += b; }
        }
        float sp = __shfl(cp, 63, 64);
        float st = __shfl(ct, 63, 64);
        float diff = fabsf(cp / (sp + 1e-8f) - ct / (st + 1e-8f));
        #pragma unroll
        for (int off = 32; off; off >>= 1)
            diff += __shfl_xor(diff, off, 64);
        if (s == 0) {
            partial[ci] = diff;
            __threadfence();                       // release partial[ci]
            uint32_t old = atomicAdd(ticket, 1u);  // device-scope
            if (old == NCH - 1) {                  // last pair-block finishes
                __threadfence();                   // acquire others' partials
                float acc = 0.0f;
                #pragma unroll
                for (int i = 0; i < NCH; ++i) acc += partial[i];
                out[0] = acc / (float)(NCH * BINS);
            }
        }
    }
}

extern "C" void kernel_launch(void* const* d_in, const int* in_sizes, int n_in,
                              void* d_out, int out_size, void* d_ws, size_t ws_size,
                              hipStream_t stream)
{
    const float* pred   = (const float*)d_in[0];
    const float* target = (const float*)d_in[1];
    uint32_t* part    = (uint32_t*)d_ws;                          // 24*32*192 u32
    float*    partial = (float*)(part + (size_t)NIMG * CHUNKS * SBINS); // 12 f32
    uint32_t* ticket  = (uint32_t*)(partial + NCH);               // 1 u32

    hist_kernel<<<dim3(CHUNKS, NCH, 2), THREADS, 0, stream>>>(pred, target, part, ticket);
    conv_fin_kernel<<<NCH, 256, 0, stream>>>(part, partial, ticket, (float*)d_out);
}